// Round 7
// baseline (457.327 us; speedup 1.0000x reference)
//
#include <hip/hip_runtime.h>
#include <math.h>

#define EPS  1e-7f
#define MAXT 0.999999f   // 1 - 1e-6

typedef short  s16x8  __attribute__((ext_vector_type(8)));
typedef float  f32x16 __attribute__((ext_vector_type(16)));

__device__ __forceinline__ float waveRedSum(float v) {
    #pragma unroll
    for (int off = 32; off > 0; off >>= 1)
        v += __shfl_xor(v, off, 64);
    return v;
}

__device__ __forceinline__ unsigned short f2bf(float f) {
    unsigned u = __float_as_uint(f);
    u += 0x7fff + ((u >> 16) & 1);          // RNE, inputs are finite
    return (unsigned short)(u >> 16);
}

// packed fp32x2 -> bf16x2 (RNE), single HW instruction on gfx950
__device__ __forceinline__ unsigned cvt_pk_bf16(float lo, float hi) {
    unsigned r;
    asm("v_cvt_pk_bf16_f32 %0, %1, %2" : "=v"(r) : "v"(lo), "v"(hi));
    return r;
}

// async 16B global->LDS DMA (dest = wave-uniform base + lane*16)
__device__ __forceinline__ void async_cp16(const float* src, void* ldsbase) {
    __builtin_amdgcn_global_load_lds(
        (const __attribute__((address_space(1))) unsigned int*)src,
        (__attribute__((address_space(3))) unsigned int*)ldsbase,
        16, 0, 0);
}

// phase-A tail: exp0 -> h_add(bias) -> log0 -> pack bf16 (MFMA-B layout)
__device__ __forceinline__ void tangent_pack(float a0, float a1, float bx, float by,
                                             float y2, int row, int c0,
                                             unsigned short* __restrict__ vpack) {
    float np2 = waveRedSum(a0*a0 + a1*a1);
    float np  = fmaxf(sqrtf(np2), EPS);
    float se  = tanhf(np)/np;
    float h0 = a0*se, h1 = a1*se;
    float x2 = np2*se*se;
    float xy = waveRedSum(h0*bx + h1*by);
    float den = fmaxf(1.f + 2.f*xy + x2*y2, EPS);
    float cx = 1.f + 2.f*xy + y2;
    float cy = 1.f - x2;
    float hb0 = (cx*h0 + cy*bx)/den, hb1 = (cx*h1 + cy*by)/den;
    float m2 = waveRedSum(hb0*hb0 + hb1*hb1);
    float mm = fmaxf(sqrtf(m2), EPS);
    float sl = atanhf(fminf(mm, MAXT))/mm;
    const int tbase = (row >> 4)*2048 + (row & 15);
    vpack[tbase + c0*16]       = f2bf(hb0*sl);
    vpack[tbase + (c0+1)*16]   = f2bf(hb1*sl);
}

// phase-C tail: exp0 -> h_add(bias) -> store
__device__ __forceinline__ void final_out(float a0, float a1, float bx, float by,
                                          float y2, int row, int c0,
                                          float* __restrict__ out) {
    float np2 = waveRedSum(a0*a0 + a1*a1);
    float np  = fmaxf(sqrtf(np2), EPS);
    float so  = tanhf(np)/np;
    float o0 = a0*so, o1 = a1*so;
    float x2 = np2*so*so;
    float xy = waveRedSum(o0*bx + o1*by);
    float den = fmaxf(1.f + 2.f*xy + x2*y2, EPS);
    float cx = 1.f + 2.f*xy + y2;
    float cy = 1.f - x2;
    float2 res;
    res.x = (cx*o0 + cy*bx)/den;
    res.y = (cx*o1 + cy*by)/den;
    *(float2*)(out + (size_t)row*128 + c0) = res;
}

// ---------------------------------------------------------------------------
// Kernel A: vpack = log0( h_add( exp0( log0(x) @ embed ), embed_bias ) )
// 8 rows/wave: embed L2 traffic 512 MB (1-row) -> 64 MB; 256 blocks.
// ---------------------------------------------------------------------------
__global__ __launch_bounds__(256) void kA(const float* __restrict__ x,
                                          const float* __restrict__ embed,
                                          const float* __restrict__ ebias,
                                          unsigned short* __restrict__ vpack) {
    __shared__ float u[4][8][128];                 // 16 KB
    const int wave = threadIdx.x >> 6;
    const int lane = threadIdx.x & 63;
    const int row0 = blockIdx.x * 32 + wave * 8;   // rows row0 .. row0+7
    const int c0   = lane * 2;

    #pragma unroll
    for (int r = 0; r < 8; r++) {
        const int row = row0 + r;
        float2 xr = *(const float2*)(x + (size_t)row * 128 + c0);
        float n2 = waveRedSum(xr.x*xr.x + xr.y*xr.y);
        float nn = fmaxf(sqrtf(n2), EPS);
        float sc = atanhf(fminf(nn, MAXT))/nn;
        u[wave][r][c0]     = xr.x*sc;
        u[wave][r][c0 + 1] = xr.y*sc;
    }
    __syncthreads();

    float a0[8] = {0.f}, a1[8] = {0.f};
    #pragma unroll 4
    for (int k = 0; k < 128; k++) {
        float2 e = *(const float2*)(embed + (size_t)k * 128 + c0);
        #pragma unroll
        for (int r = 0; r < 8; r++) {
            float uk = u[wave][r][k];
            a0[r] = fmaf(uk, e.x, a0[r]);
            a1[r] = fmaf(uk, e.y, a1[r]);
        }
    }
    float bx = ebias[c0], by = ebias[c0 + 1];
    float y2 = waveRedSum(bx*bx + by*by);          // row-invariant
    #pragma unroll
    for (int r = 0; r < 8; r++)
        tangent_pack(a0[r], a1[r], bx, by, y2, row0 + r, c0, vpack);
}

// ---------------------------------------------------------------------------
// Kernel B: t = adj @ v  (bf16 MFMA, fp32 out), DMA pipeline.
// Verified structure (rounds 3/5/6) — UNCHANGED; three compute-side variants
// were flat, so kB sits at its HBM floor (~50 us for the 268 MB adj read).
// ---------------------------------------------------------------------------
#define BK 128

__global__ __launch_bounds__(256, 4) void kB(const float* __restrict__ adj,
                                             const unsigned short* __restrict__ vpack,
                                             float* __restrict__ tpart,
                                             int klen) {
    __shared__ __align__(16) float Af[2][32][128];   // 2 x 16 KB
    const int tid  = threadIdx.x;
    const int wave = tid >> 6;
    const int lane = tid & 63;
    const int r0   = blockIdx.x * 32;
    const int k0   = blockIdx.y * klen;
    float* tout    = tpart + (size_t)blockIdx.y * 8192 * 128;

    // DMA: issue i = wave*4+j covers LDS rows {2i, 2i+1} (1 KB each issue).
    const int rpar = lane >> 5;
    const int cst  = lane & 31;

    // MFMA fragment indexing
    const int m  = lane & 31;       // A row / output row-within-tile
    const int kh = lane >> 5;       // k-half
    const int n  = wave * 32 + m;   // output col
    const int sw = m & 7;           // read-side chunk swizzle
    const unsigned short* vb = vpack + (size_t)n * 16 + kh * 8;

    f32x16 acc = {0.f};
    const int kiters = klen / BK;

    // prologue: DMA tile 0 -> buf 0
    #pragma unroll
    for (int j = 0; j < 4; j++) {
        int i = wave * 4 + j;
        int r = 2 * i + rpar;
        const float* src = adj + (size_t)(r0 + r) * 8192 + k0 + ((cst ^ (r & 7)) << 2);
        async_cp16(src, (char*)&Af[0][0][0] + i * 1024);
    }
    __syncthreads();

    for (int it = 0; it < kiters; it++) {
        const int cur = it & 1;
        const int ktile0 = (k0 + it * BK) >> 4;

        // (1) preload this tile's B fragments (oldest in vmcnt queue)
        s16x8 bfr[8];
        #pragma unroll
        for (int kk = 0; kk < 8; kk++)
            bfr[kk] = *(const s16x8*)(vb + (size_t)(ktile0 + kk) * 2048);

        // (2) issue DMA for tile it+1 into the other buffer
        if (it + 1 < kiters) {
            #pragma unroll
            for (int j = 0; j < 4; j++) {
                int i = wave * 4 + j;
                int r = 2 * i + rpar;
                const float* src = adj + (size_t)(r0 + r) * 8192 + k0 + (it + 1) * BK
                                 + ((cst ^ (r & 7)) << 2);
                async_cp16(src, (char*)&Af[cur ^ 1][0][0] + i * 1024);
            }
        }

        // (3) compute on buf cur: swizzled ds_read, cvt_pk, MFMA
        #pragma unroll
        for (int kk = 0; kk < 8; kk++) {
            const int q0 = kk * 4 + kh * 2;
            const float4 lo = *(const float4*)&Af[cur][m][(q0 ^ sw) << 2];
            const float4 hi = *(const float4*)&Af[cur][m][((q0 + 1) ^ sw) << 2];
            union { unsigned u[4]; s16x8 v; } p;
            p.u[0] = cvt_pk_bf16(lo.x, lo.y);
            p.u[1] = cvt_pk_bf16(lo.z, lo.w);
            p.u[2] = cvt_pk_bf16(hi.x, hi.y);
            p.u[3] = cvt_pk_bf16(hi.z, hi.w);
            acc = __builtin_amdgcn_mfma_f32_32x32x16_bf16(p.v, bfr[kk], acc, 0, 0, 0);
        }

        __syncthreads();   // drains DMA (vmcnt 0) + all readers done with cur
    }

    // epilogue: C/D layout col=lane&31, row=(r&3)+8*(r>>2)+4*(lane>>5)
    #pragma unroll
    for (int r = 0; r < 16; r++) {
        int row = r0 + (r & 3) + 8 * (r >> 2) + 4 * kh;
        tout[(size_t)row * 128 + n] = acc[r];
    }
}

// ---------------------------------------------------------------------------
// Kernel C: out = h_add( exp0( log0([x ; exp0(sum tpart)]) @ layer ), lbias )
// 8 rows/wave: layer L2 traffic 1 GB (1-row) -> 128 MB; 256 blocks.
// ---------------------------------------------------------------------------
#define SPLITS 8

__global__ __launch_bounds__(256) void kC(const float* __restrict__ x,
                                          const float* __restrict__ tpart,
                                          const float* __restrict__ layer,
                                          const float* __restrict__ lbias,
                                          float* __restrict__ out) {
    __shared__ float w[4][8][256];                 // 32 KB
    const int wave = threadIdx.x >> 6;
    const int lane = threadIdx.x & 63;
    const int row0 = blockIdx.x * 32 + wave * 8;   // rows row0 .. row0+7
    const int c0   = lane * 2;

    #pragma unroll
    for (int r = 0; r < 8; r++) {
        const int row = row0 + r;
        float2 tr = *(const float2*)(tpart + (size_t)row * 128 + c0);
        #pragma unroll
        for (int s = 1; s < SPLITS; s++) {
            float2 p = *(const float2*)(tpart + (size_t)s * 8192 * 128
                                        + (size_t)row * 128 + c0);
            tr.x += p.x; tr.y += p.y;
        }
        const float2 xr = *(const float2*)(x + (size_t)row * 128 + c0);
        float st = waveRedSum(tr.x*tr.x + tr.y*tr.y);
        float sx = waveRedSum(xr.x*xr.x + xr.y*xr.y);
        float nt = fmaxf(sqrtf(st), EPS);
        float se = tanhf(nt)/nt;
        float ncat2 = sx + st*se*se;
        float ncat  = fmaxf(sqrtf(ncat2), EPS);
        float swl   = atanhf(fminf(ncat, MAXT))/ncat;
        w[wave][r][c0]         = xr.x*swl;
        w[wave][r][c0+1]       = xr.y*swl;
        w[wave][r][128 + c0]   = tr.x*se*swl;
        w[wave][r][128 + c0+1] = tr.y*se*swl;
    }
    __syncthreads();

    float a0[8] = {0.f}, a1[8] = {0.f};
    #pragma unroll 4
    for (int k = 0; k < 256; k++) {
        float2 e = *(const float2*)(layer + (size_t)k * 128 + c0);
        #pragma unroll
        for (int r = 0; r < 8; r++) {
            float wk = w[wave][r][k];
            a0[r] = fmaf(wk, e.x, a0[r]);
            a1[r] = fmaf(wk, e.y, a1[r]);
        }
    }
    float bx = lbias[c0], by = lbias[c0 + 1];
    float y2 = waveRedSum(bx*bx + by*by);
    #pragma unroll
    for (int r = 0; r < 8; r++)
        final_out(a0[r], a1[r], bx, by, y2, row0 + r, c0, out);
}

// ---------------------------------------------------------------------------
extern "C" void kernel_launch(void* const* d_in, const int* in_sizes, int n_in,
                              void* d_out, int out_size, void* d_ws, size_t ws_size,
                              hipStream_t stream) {
    const float* x     = (const float*)d_in[0];   // [8192,128]
    const float* adj   = (const float*)d_in[1];   // [8192,8192]
    const float* embed = (const float*)d_in[2];   // [128,128]
    const float* layer = (const float*)d_in[3];   // [256,128]
    const float* eb    = (const float*)d_in[4];   // [128]
    const float* lb    = (const float*)d_in[5];   // [128]
    float* out = (float*)d_out;

    const size_t vbytes = (size_t)8192 * 128 * 2;          // 2 MB bf16 packed
    unsigned short* vpack = (unsigned short*)d_ws;
    float* tpart = (float*)((char*)d_ws + vbytes);

    kA<<<256, 256, 0, stream>>>(x, embed, eb, vpack);
    kB<<<dim3(256, SPLITS), 256, 0, stream>>>(adj, vpack, tpart, 8192 / SPLITS);
    kC<<<256, 256, 0, stream>>>(x, tpart, layer, lb, out);
}

// Round 8
// 427.331 us; speedup vs baseline: 1.0702x; 1.0702x over previous
//
#include <hip/hip_runtime.h>
#include <math.h>

#define EPS  1e-7f
#define MAXT 0.999999f   // 1 - 1e-6

typedef short  s16x8  __attribute__((ext_vector_type(8)));
typedef float  f32x16 __attribute__((ext_vector_type(16)));

__device__ __forceinline__ float waveRedSum(float v) {
    #pragma unroll
    for (int off = 32; off > 0; off >>= 1)
        v += __shfl_xor(v, off, 64);
    return v;
}

__device__ __forceinline__ unsigned short f2bf(float f) {
    unsigned u = __float_as_uint(f);
    u += 0x7fff + ((u >> 16) & 1);          // RNE, inputs are finite
    return (unsigned short)(u >> 16);
}

// packed fp32x2 -> bf16x2 (RNE), single HW instruction on gfx950
__device__ __forceinline__ unsigned cvt_pk_bf16(float lo, float hi) {
    unsigned r;
    asm("v_cvt_pk_bf16_f32 %0, %1, %2" : "=v"(r) : "v"(lo), "v"(hi));
    return r;
}

// async 16B global->LDS DMA (dest = wave-uniform base + lane*16)
__device__ __forceinline__ void async_cp16(const float* src, void* ldsbase) {
    __builtin_amdgcn_global_load_lds(
        (const __attribute__((address_space(1))) unsigned int*)src,
        (__attribute__((address_space(3))) unsigned int*)ldsbase,
        16, 0, 0);
}

// phase-A tail: exp0 -> h_add(bias) -> log0 -> pack bf16 (MFMA-B layout)
__device__ __forceinline__ void tangent_pack(float a0, float a1, float bx, float by,
                                             float y2, int row, int c0,
                                             unsigned short* __restrict__ vpack) {
    float np2 = waveRedSum(a0*a0 + a1*a1);
    float np  = fmaxf(sqrtf(np2), EPS);
    float se  = tanhf(np)/np;
    float h0 = a0*se, h1 = a1*se;
    float x2 = np2*se*se;
    float xy = waveRedSum(h0*bx + h1*by);
    float den = fmaxf(1.f + 2.f*xy + x2*y2, EPS);
    float cx = 1.f + 2.f*xy + y2;
    float cy = 1.f - x2;
    float hb0 = (cx*h0 + cy*bx)/den, hb1 = (cx*h1 + cy*by)/den;
    float m2 = waveRedSum(hb0*hb0 + hb1*hb1);
    float mm = fmaxf(sqrtf(m2), EPS);
    float sl = atanhf(fminf(mm, MAXT))/mm;
    const int tbase = (row >> 4)*2048 + (row & 15);
    vpack[tbase + c0*16]       = f2bf(hb0*sl);
    vpack[tbase + (c0+1)*16]   = f2bf(hb1*sl);
}

// phase-C tail: exp0 -> h_add(bias) -> store
__device__ __forceinline__ void final_out(float a0, float a1, float bx, float by,
                                          float y2, int row, int c0,
                                          float* __restrict__ out) {
    float np2 = waveRedSum(a0*a0 + a1*a1);
    float np  = fmaxf(sqrtf(np2), EPS);
    float so  = tanhf(np)/np;
    float o0 = a0*so, o1 = a1*so;
    float x2 = np2*so*so;
    float xy = waveRedSum(o0*bx + o1*by);
    float den = fmaxf(1.f + 2.f*xy + x2*y2, EPS);
    float cx = 1.f + 2.f*xy + y2;
    float cy = 1.f - x2;
    float2 res;
    res.x = (cx*o0 + cy*bx)/den;
    res.y = (cx*o1 + cy*by)/den;
    *(float2*)(out + (size_t)row*128 + c0) = res;
}

// ---------------------------------------------------------------------------
// Kernel A: vpack = log0( h_add( exp0( log0(x) @ embed ), embed_bias ) )
// 4 rows/wave (round-6 optimum: 512 blocks = 2 waves/SIMD for latency hiding;
// 8 rows/wave at 256 blocks regressed +30 us — occupancy cliff).
// Unroll 8: doubles in-flight L2 weight loads per wave.
// ---------------------------------------------------------------------------
__global__ __launch_bounds__(256) void kA(const float* __restrict__ x,
                                          const float* __restrict__ embed,
                                          const float* __restrict__ ebias,
                                          unsigned short* __restrict__ vpack) {
    __shared__ float u[4][4][128];
    const int wave = threadIdx.x >> 6;
    const int lane = threadIdx.x & 63;
    const int row0 = blockIdx.x * 16 + wave * 4;   // rows row0 .. row0+3
    const int c0   = lane * 2;

    #pragma unroll
    for (int r = 0; r < 4; r++) {
        const int row = row0 + r;
        float2 xr = *(const float2*)(x + (size_t)row * 128 + c0);
        float n2 = waveRedSum(xr.x*xr.x + xr.y*xr.y);
        float nn = fmaxf(sqrtf(n2), EPS);
        float sc = atanhf(fminf(nn, MAXT))/nn;
        u[wave][r][c0]     = xr.x*sc;
        u[wave][r][c0 + 1] = xr.y*sc;
    }
    __syncthreads();

    float a0[4] = {0.f,0.f,0.f,0.f}, a1[4] = {0.f,0.f,0.f,0.f};
    #pragma unroll 8
    for (int k = 0; k < 128; k++) {
        float2 e = *(const float2*)(embed + (size_t)k * 128 + c0);
        #pragma unroll
        for (int r = 0; r < 4; r++) {
            float uk = u[wave][r][k];
            a0[r] = fmaf(uk, e.x, a0[r]);
            a1[r] = fmaf(uk, e.y, a1[r]);
        }
    }
    float bx = ebias[c0], by = ebias[c0 + 1];
    float y2 = waveRedSum(bx*bx + by*by);          // row-invariant
    #pragma unroll
    for (int r = 0; r < 4; r++)
        tangent_pack(a0[r], a1[r], bx, by, y2, row0 + r, c0, vpack);
}

// ---------------------------------------------------------------------------
// Kernel B: t = adj @ v  (bf16 MFMA, fp32 out), DMA pipeline.
// Verified structure (rounds 3/5/6/7) — UNCHANGED; three compute-side
// variants were flat, so kB sits at its HBM floor for this structure.
// ---------------------------------------------------------------------------
#define BK 128

__global__ __launch_bounds__(256, 4) void kB(const float* __restrict__ adj,
                                             const unsigned short* __restrict__ vpack,
                                             float* __restrict__ tpart,
                                             int klen) {
    __shared__ __align__(16) float Af[2][32][128];   // 2 x 16 KB
    const int tid  = threadIdx.x;
    const int wave = tid >> 6;
    const int lane = tid & 63;
    const int r0   = blockIdx.x * 32;
    const int k0   = blockIdx.y * klen;
    float* tout    = tpart + (size_t)blockIdx.y * 8192 * 128;

    // DMA: issue i = wave*4+j covers LDS rows {2i, 2i+1} (1 KB each issue).
    const int rpar = lane >> 5;
    const int cst  = lane & 31;

    // MFMA fragment indexing
    const int m  = lane & 31;       // A row / output row-within-tile
    const int kh = lane >> 5;       // k-half
    const int n  = wave * 32 + m;   // output col
    const int sw = m & 7;           // read-side chunk swizzle
    const unsigned short* vb = vpack + (size_t)n * 16 + kh * 8;

    f32x16 acc = {0.f};
    const int kiters = klen / BK;

    // prologue: DMA tile 0 -> buf 0
    #pragma unroll
    for (int j = 0; j < 4; j++) {
        int i = wave * 4 + j;
        int r = 2 * i + rpar;
        const float* src = adj + (size_t)(r0 + r) * 8192 + k0 + ((cst ^ (r & 7)) << 2);
        async_cp16(src, (char*)&Af[0][0][0] + i * 1024);
    }
    __syncthreads();

    for (int it = 0; it < kiters; it++) {
        const int cur = it & 1;
        const int ktile0 = (k0 + it * BK) >> 4;

        // (1) preload this tile's B fragments (oldest in vmcnt queue)
        s16x8 bfr[8];
        #pragma unroll
        for (int kk = 0; kk < 8; kk++)
            bfr[kk] = *(const s16x8*)(vb + (size_t)(ktile0 + kk) * 2048);

        // (2) issue DMA for tile it+1 into the other buffer
        if (it + 1 < kiters) {
            #pragma unroll
            for (int j = 0; j < 4; j++) {
                int i = wave * 4 + j;
                int r = 2 * i + rpar;
                const float* src = adj + (size_t)(r0 + r) * 8192 + k0 + (it + 1) * BK
                                 + ((cst ^ (r & 7)) << 2);
                async_cp16(src, (char*)&Af[cur ^ 1][0][0] + i * 1024);
            }
        }

        // (3) compute on buf cur: swizzled ds_read, cvt_pk, MFMA
        #pragma unroll
        for (int kk = 0; kk < 8; kk++) {
            const int q0 = kk * 4 + kh * 2;
            const float4 lo = *(const float4*)&Af[cur][m][(q0 ^ sw) << 2];
            const float4 hi = *(const float4*)&Af[cur][m][((q0 + 1) ^ sw) << 2];
            union { unsigned u[4]; s16x8 v; } p;
            p.u[0] = cvt_pk_bf16(lo.x, lo.y);
            p.u[1] = cvt_pk_bf16(lo.z, lo.w);
            p.u[2] = cvt_pk_bf16(hi.x, hi.y);
            p.u[3] = cvt_pk_bf16(hi.z, hi.w);
            acc = __builtin_amdgcn_mfma_f32_32x32x16_bf16(p.v, bfr[kk], acc, 0, 0, 0);
        }

        __syncthreads();   // drains DMA (vmcnt 0) + all readers done with cur
    }

    // epilogue: C/D layout col=lane&31, row=(r&3)+8*(r>>2)+4*(lane>>5)
    #pragma unroll
    for (int r = 0; r < 16; r++) {
        int row = r0 + (r & 3) + 8 * (r >> 2) + 4 * kh;
        tout[(size_t)row * 128 + n] = acc[r];
    }
}

// ---------------------------------------------------------------------------
// Kernel C: out = h_add( exp0( log0([x ; exp0(sum tpart)]) @ layer ), lbias )
// 4 rows/wave (round-6 optimum); unroll 8 for deeper L2-load pipelining.
// ---------------------------------------------------------------------------
#define SPLITS 8

__global__ __launch_bounds__(256) void kC(const float* __restrict__ x,
                                          const float* __restrict__ tpart,
                                          const float* __restrict__ layer,
                                          const float* __restrict__ lbias,
                                          float* __restrict__ out) {
    __shared__ float w[4][4][256];
    const int wave = threadIdx.x >> 6;
    const int lane = threadIdx.x & 63;
    const int row0 = blockIdx.x * 16 + wave * 4;   // rows row0 .. row0+3
    const int c0   = lane * 2;

    #pragma unroll
    for (int r = 0; r < 4; r++) {
        const int row = row0 + r;
        float2 tr = *(const float2*)(tpart + (size_t)row * 128 + c0);
        #pragma unroll
        for (int s = 1; s < SPLITS; s++) {
            float2 p = *(const float2*)(tpart + (size_t)s * 8192 * 128
                                        + (size_t)row * 128 + c0);
            tr.x += p.x; tr.y += p.y;
        }
        const float2 xr = *(const float2*)(x + (size_t)row * 128 + c0);
        float st = waveRedSum(tr.x*tr.x + tr.y*tr.y);
        float sx = waveRedSum(xr.x*xr.x + xr.y*xr.y);
        float nt = fmaxf(sqrtf(st), EPS);
        float se = tanhf(nt)/nt;
        float ncat2 = sx + st*se*se;
        float ncat  = fmaxf(sqrtf(ncat2), EPS);
        float swl   = atanhf(fminf(ncat, MAXT))/ncat;
        w[wave][r][c0]         = xr.x*swl;
        w[wave][r][c0+1]       = xr.y*swl;
        w[wave][r][128 + c0]   = tr.x*se*swl;
        w[wave][r][128 + c0+1] = tr.y*se*swl;
    }
    __syncthreads();

    float a0[4] = {0.f,0.f,0.f,0.f}, a1[4] = {0.f,0.f,0.f,0.f};
    #pragma unroll 8
    for (int k = 0; k < 256; k++) {
        float2 e = *(const float2*)(layer + (size_t)k * 128 + c0);
        #pragma unroll
        for (int r = 0; r < 4; r++) {
            float wk = w[wave][r][k];
            a0[r] = fmaf(wk, e.x, a0[r]);
            a1[r] = fmaf(wk, e.y, a1[r]);
        }
    }
    float bx = lbias[c0], by = lbias[c0 + 1];
    float y2 = waveRedSum(bx*bx + by*by);
    #pragma unroll
    for (int r = 0; r < 4; r++)
        final_out(a0[r], a1[r], bx, by, y2, row0 + r, c0, out);
}

// ---------------------------------------------------------------------------
extern "C" void kernel_launch(void* const* d_in, const int* in_sizes, int n_in,
                              void* d_out, int out_size, void* d_ws, size_t ws_size,
                              hipStream_t stream) {
    const float* x     = (const float*)d_in[0];   // [8192,128]
    const float* adj   = (const float*)d_in[1];   // [8192,8192]
    const float* embed = (const float*)d_in[2];   // [128,128]
    const float* layer = (const float*)d_in[3];   // [256,128]
    const float* eb    = (const float*)d_in[4];   // [128]
    const float* lb    = (const float*)d_in[5];   // [128]
    float* out = (float*)d_out;

    const size_t vbytes = (size_t)8192 * 128 * 2;          // 2 MB bf16 packed
    unsigned short* vpack = (unsigned short*)d_ws;
    float* tpart = (float*)((char*)d_ws + vbytes);

    kA<<<512, 256, 0, stream>>>(x, embed, eb, vpack);
    kB<<<dim3(256, SPLITS), 256, 0, stream>>>(adj, vpack, tpart, 8192 / SPLITS);
    kC<<<512, 256, 0, stream>>>(x, tpart, layer, lb, out);
}